// Round 2
// baseline (162.726 us; speedup 1.0000x reference)
//
#include <hip/hip_runtime.h>
#include <hip/hip_bf16.h>

#define Bq 4
#define Tq 4096
#define Cq 512
#define Hq 64
#define KC 512           // k-chunk width per wave (16 tiles of 32)
#define NCH_MAX 8        // 4096 / 512

using bf16  = __bf16;
using bf16x8 = __attribute__((ext_vector_type(8))) __bf16;
using bf16x4 = __attribute__((ext_vector_type(4))) __bf16;
using f32x4  = __attribute__((ext_vector_type(4))) float;

// ---------------------------------------------------------------------------
// Kernel 1: transpose + bf16-cast the three weight matrices: WT[t][h][c]
// ---------------------------------------------------------------------------
__global__ __launch_bounds__(256) void prep_weights_kernel(
    const float* __restrict__ kW, const float* __restrict__ qW,
    const float* __restrict__ vW, bf16* __restrict__ WT)
{
    int i = blockIdx.x * 256 + threadIdx.x;   // 3*64*512 = 98304 total
    int t = i >> 15;
    int r = i & 32767;
    int h = r >> 9;
    int c = r & 511;
    const float* W = (t == 0) ? kW : (t == 1) ? qW : vW;
    WT[i] = (bf16)W[c * Hq + h];
}

// ---------------------------------------------------------------------------
// Kernel 2: projections via MFMA 16x16x32 bf16 (unchanged from round 1).
// ---------------------------------------------------------------------------
__global__ __launch_bounds__(256) void proj_kernel(
    const float* __restrict__ Xk, const float* __restrict__ Xq,
    const float* __restrict__ Xv, const bf16* __restrict__ WT,
    const float* __restrict__ bk, const float* __restrict__ bq,
    const float* __restrict__ bv,
    bf16* __restrict__ kp, bf16* __restrict__ qp, bf16* __restrict__ vpT)
{
    const int t    = blockIdx.y;
    const int lane = threadIdx.x & 63;
    const int wave = threadIdx.x >> 6;
    const int lq   = lane & 15;
    const int lg   = lane >> 4;
    const int row0 = blockIdx.x * 64 + wave * 16;

    const float* X    = (t == 0) ? Xk : (t == 1) ? Xq : Xv;
    const float* bias = (t == 0) ? bk : (t == 1) ? bq : bv;
    const bf16*  Wt   = WT + (size_t)t * (Hq * Cq);

    const float* Xrow = X + (size_t)(row0 + lq) * Cq + lg * 8;

    f32x4 acc[4];
#pragma unroll
    for (int i = 0; i < 4; ++i) acc[i] = f32x4{0.f, 0.f, 0.f, 0.f};

    for (int kc = 0; kc < Cq; kc += 32) {
        float4 a0 = *(const float4*)(Xrow + kc);
        float4 a1 = *(const float4*)(Xrow + kc + 4);
        bf16x8 af;
        af[0] = (bf16)a0.x; af[1] = (bf16)a0.y; af[2] = (bf16)a0.z; af[3] = (bf16)a0.w;
        af[4] = (bf16)a1.x; af[5] = (bf16)a1.y; af[6] = (bf16)a1.z; af[7] = (bf16)a1.w;
#pragma unroll
        for (int ht = 0; ht < 4; ++ht) {
            bf16x8 bfB = *(const bf16x8*)(Wt + (size_t)(ht * 16 + lq) * Cq + kc + lg * 8);
            acc[ht] = __builtin_amdgcn_mfma_f32_16x16x32_bf16(af, bfB, acc[ht], 0, 0, 0);
        }
    }

    const float scale = (t == 1) ? 0.044194173824159216f : 1.0f;

    if (t < 2) {
        bf16* dst = (t == 0) ? kp : qp;
#pragma unroll
        for (int ht = 0; ht < 4; ++ht) {
            float bb = bias[ht * 16 + lq];
#pragma unroll
            for (int r = 0; r < 4; ++r) {
                int row = row0 + 4 * lg + r;
                dst[(size_t)row * Hq + ht * 16 + lq] = (bf16)((acc[ht][r] + bb) * scale);
            }
        }
    } else {
#pragma unroll
        for (int ht = 0; ht < 4; ++ht) {
            float bb = bias[ht * 16 + lq];
            bf16x4 pk;
#pragma unroll
            for (int r = 0; r < 4; ++r) pk[r] = (bf16)(acc[ht][r] + bb);
            int rowg = row0 + 4 * lg;
            int bidx = rowg >> 12;
            int tt   = rowg & 4095;
            int h    = ht * 16 + lq;
            *(bf16x4*)(vpT + (((size_t)(bidx * Hq + h)) << 12) + tt) = pk;
        }
    }
}

// ---------------------------------------------------------------------------
// Kernel 3: causal flash attention, SPLIT-K.
// One wave per (b, q-tile of 16 rows, k-chunk of 512).  Same verified inner
// loop as round 1 (swapped QK^T, lane-local online softmax, P through padded
// LDS).  Epilogue writes NORMALIZED partial (o/l in bf16) + (m, l in f32) to
// workspace; combine_kernel merges the <=8 chunks per q-tile.
// grid = (1024, 8); blocks with chunk start beyond the diagonal exit.
// ---------------------------------------------------------------------------
__global__ __launch_bounds__(64) void attn_kernel(
    const bf16* __restrict__ qp, const bf16* __restrict__ kp,
    const bf16* __restrict__ vpT,
    bf16* __restrict__ PO, float* __restrict__ PML)
{
    __shared__ bf16 P_lds[16][40];

    const int gid  = blockIdx.x;
    const int b    = gid & 3;
    const int qt   = gid >> 2;
    const int qb_  = qt * 16;
    const int c    = blockIdx.y;
    if (c * KC > qb_) return;                 // chunk entirely above diagonal

    const int lane = threadIdx.x;
    const int lq   = lane & 15;
    const int lg   = lane >> 4;

    const bf16* qrow = qp + ((size_t)b * Tq + qb_ + lq) * Hq + lg * 8;
    const bf16x8 Qf0 = *(const bf16x8*)(qrow);
    const bf16x8 Qf1 = *(const bf16x8*)(qrow + 32);

    const bf16* Kb = kp  + (size_t)b * Tq * Hq;
    const bf16* Vb = vpT + (size_t)b * Hq * Tq;

    f32x4 o[4];
#pragma unroll
    for (int i = 0; i < 4; ++i) o[i] = f32x4{0.f, 0.f, 0.f, 0.f};
    float m = -INFINITY, l = 0.f;

    const int nfull = qb_ >> 5;               // last (diagonal) tile index
    const int t0 = c * (KC / 32);
    const int t1 = min(nfull, t0 + (KC / 32) - 1);

    for (int it = t0; it <= t1; ++it) {
        const int kb0 = it * 32;

        f32x4 s0, s1;
        {
            const bf16* kr = Kb + (size_t)(kb0 + lq) * Hq + lg * 8;
            bf16x8 a0 = *(const bf16x8*)(kr);
            bf16x8 a1 = *(const bf16x8*)(kr + 32);
            f32x4 z = f32x4{0.f, 0.f, 0.f, 0.f};
            s0 = __builtin_amdgcn_mfma_f32_16x16x32_bf16(a0, Qf0, z, 0, 0, 0);
            s0 = __builtin_amdgcn_mfma_f32_16x16x32_bf16(a1, Qf1, s0, 0, 0, 0);
        }
        {
            const bf16* kr = Kb + (size_t)(kb0 + 16 + lq) * Hq + lg * 8;
            bf16x8 a0 = *(const bf16x8*)(kr);
            bf16x8 a1 = *(const bf16x8*)(kr + 32);
            f32x4 z = f32x4{0.f, 0.f, 0.f, 0.f};
            s1 = __builtin_amdgcn_mfma_f32_16x16x32_bf16(a0, Qf0, z, 0, 0, 0);
            s1 = __builtin_amdgcn_mfma_f32_16x16x32_bf16(a1, Qf1, s1, 0, 0, 0);
        }

        if (it == nfull) {
            const int qg = qb_ + lq;
#pragma unroll
            for (int r = 0; r < 4; ++r) {
                if (kb0 + 4 * lg + r > qg)      s0[r] = -INFINITY;
                if (kb0 + 16 + 4 * lg + r > qg) s1[r] = -INFINITY;
            }
        }

        float tmax = fmaxf(fmaxf(fmaxf(s0[0], s0[1]), fmaxf(s0[2], s0[3])),
                           fmaxf(fmaxf(s1[0], s1[1]), fmaxf(s1[2], s1[3])));
        tmax = fmaxf(tmax, __shfl_xor(tmax, 16, 64));
        tmax = fmaxf(tmax, __shfl_xor(tmax, 32, 64));
        const float mnew = fmaxf(m, tmax);
        const float corr = __expf(m - mnew);
        float p0[4], p1[4];
#pragma unroll
        for (int r = 0; r < 4; ++r) {
            p0[r] = __expf(s0[r] - mnew);
            p1[r] = __expf(s1[r] - mnew);
        }
        float psum = (p0[0] + p0[1] + p0[2] + p0[3]) + (p1[0] + p1[1] + p1[2] + p1[3]);
        psum += __shfl_xor(psum, 16, 64);
        psum += __shfl_xor(psum, 32, 64);
        l = l * corr + psum;
        m = mnew;
#pragma unroll
        for (int ht = 0; ht < 4; ++ht) {
            o[ht][0] *= corr; o[ht][1] *= corr; o[ht][2] *= corr; o[ht][3] *= corr;
        }

        bf16x4 w0, w1;
#pragma unroll
        for (int r = 0; r < 4; ++r) { w0[r] = (bf16)p0[r]; w1[r] = (bf16)p1[r]; }
        *(bf16x4*)(&P_lds[lq][4 * lg])      = w0;
        *(bf16x4*)(&P_lds[lq][16 + 4 * lg]) = w1;
        const bf16x8 Pf = *(const bf16x8*)(&P_lds[lq][8 * lg]);

#pragma unroll
        for (int ht = 0; ht < 4; ++ht) {
            const bf16* vr = Vb + (size_t)(ht * 16 + lq) * Tq + kb0 + lg * 8;
            bf16x8 vf = *(const bf16x8*)(vr);
            o[ht] = __builtin_amdgcn_mfma_f32_16x16x32_bf16(vf, Pf, o[ht], 0, 0, 0);
        }
    }

    // ---- epilogue: normalized bf16 partial + (m, l) ----
    const float inv = 1.0f / l;               // l > 0 for every active chunk
    const size_t slot = (size_t)(b * 256 + qt) * NCH_MAX + c;
    bf16* po = PO + slot * (16 * 64);
#pragma unroll
    for (int ht = 0; ht < 4; ++ht) {
        bf16x4 pk;
#pragma unroll
        for (int r = 0; r < 4; ++r) pk[r] = (bf16)(o[ht][r] * inv);
        *(bf16x4*)(po + lq * 64 + ht * 16 + 4 * lg) = pk;
    }
    if (lg == 0) {
        PML[slot * 32 + lq]      = m;
        PML[slot * 32 + 16 + lq] = l;
    }
}

// ---------------------------------------------------------------------------
// Kernel 4: combine split-K partials.  64 lanes = h; 16 rows per block.
// out[row][h] = sum_c w_c * po_c[row][h],  w_c = l_c*exp(m_c-m)/L.
// ---------------------------------------------------------------------------
__global__ __launch_bounds__(64) void combine_kernel(
    const bf16* __restrict__ PO, const float* __restrict__ PML,
    float* __restrict__ out)
{
    const int gid = blockIdx.x;
    const int b   = gid & 3;
    const int qt  = gid >> 2;
    const int qb_ = qt * 16;
    const int nch = (qb_ / KC) + 1;
    const int h   = threadIdx.x;
    const size_t slot0 = (size_t)(b * 256 + qt) * NCH_MAX;

    for (int r = 0; r < 16; ++r) {
        float m = -INFINITY;
        for (int c = 0; c < nch; ++c)
            m = fmaxf(m, PML[(slot0 + c) * 32 + r]);
        float L = 0.f, acc = 0.f;
        for (int c = 0; c < nch; ++c) {
            float w = PML[(slot0 + c) * 32 + 16 + r] *
                      __expf(PML[(slot0 + c) * 32 + r] - m);
            L   += w;
            acc += w * (float)PO[(slot0 + c) * (16 * 64) + r * 64 + h];
        }
        out[((size_t)b * Tq + qb_ + r) * Hq + h] = acc / L;
    }
}

// ---------------------------------------------------------------------------
extern "C" void kernel_launch(void* const* d_in, const int* in_sizes, int n_in,
                              void* d_out, int out_size, void* d_ws, size_t ws_size,
                              hipStream_t stream)
{
    const float* k  = (const float*)d_in[0];
    const float* v  = (const float*)d_in[1];
    const float* q  = (const float*)d_in[2];
    // d_in[3] = mask: exactly tril(ones) -> causality hard-coded, never read
    const float* kW = (const float*)d_in[4];
    const float* kb = (const float*)d_in[5];
    const float* vW = (const float*)d_in[6];
    const float* vb = (const float*)d_in[7];
    const float* qW = (const float*)d_in[8];
    const float* qb = (const float*)d_in[9];
    float* out = (float*)d_out;

    // workspace layout:
    //   WT   [3][64][512] bf16      196608 B
    //   kp   [B*T][64]   bf16      2097152 B
    //   qp   [B*T][64]   bf16      2097152 B
    //   vpT  [B][64][T]  bf16      2097152 B
    //   PO   [B][256][8][16][64] bf16  16777216 B   (normalized partial o)
    //   PML  [B][256][8][2][16]  f32    1048576 B   (m, l per row)
    //   total ~24.3 MB
    char* ws = (char*)d_ws;
    bf16*  WT  = (bf16*)(ws);
    bf16*  kp  = (bf16*)(ws + 196608);
    bf16*  qp  = (bf16*)(ws + 196608 + 2097152);
    bf16*  vpT = (bf16*)(ws + 196608 + 2 * 2097152);
    bf16*  PO  = (bf16*)(ws + 196608 + 3 * 2097152);
    float* PML = (float*)(ws + 196608 + 3 * 2097152 + 16777216);

    hipLaunchKernelGGL(prep_weights_kernel, dim3(384), dim3(256), 0, stream,
                       kW, qW, vW, WT);
    hipLaunchKernelGGL(proj_kernel, dim3(256, 3), dim3(256), 0, stream,
                       k, q, v, WT, kb, qb, vb, kp, qp, vpT);
    hipLaunchKernelGGL(attn_kernel, dim3(1024, NCH_MAX), dim3(64), 0, stream,
                       qp, kp, vpT, PO, PML);
    hipLaunchKernelGGL(combine_kernel, dim3(1024), dim3(64), 0, stream,
                       PO, PML, out);
}

// Round 3
// 121.696 us; speedup vs baseline: 1.3372x; 1.3372x over previous
//
#include <hip/hip_runtime.h>
#include <hip/hip_bf16.h>

#define Bq 4
#define Tq 4096
#define Cq 512
#define Hq 64
#define KC 512           // k-chunk width per wave (16 tiles of 32)
#define NCH_MAX 8        // 4096 / 512

using bf16  = __bf16;
using bf16x8 = __attribute__((ext_vector_type(8))) __bf16;
using bf16x4 = __attribute__((ext_vector_type(4))) __bf16;
using f32x4  = __attribute__((ext_vector_type(4))) float;

// ---------------------------------------------------------------------------
// Kernel 1: transpose + bf16-cast the three weight matrices: WT[t][h][c]
// ---------------------------------------------------------------------------
__global__ __launch_bounds__(256) void prep_weights_kernel(
    const float* __restrict__ kW, const float* __restrict__ qW,
    const float* __restrict__ vW, bf16* __restrict__ WT)
{
    int i = blockIdx.x * 256 + threadIdx.x;   // 3*64*512 = 98304 total
    int t = i >> 15;
    int r = i & 32767;
    int h = r >> 9;
    int c = r & 511;
    const float* W = (t == 0) ? kW : (t == 1) ? qW : vW;
    WT[i] = (bf16)W[c * Hq + h];
}

// ---------------------------------------------------------------------------
// Kernel 2: projections via MFMA 16x16x32 bf16 (unchanged).
// ---------------------------------------------------------------------------
__global__ __launch_bounds__(256) void proj_kernel(
    const float* __restrict__ Xk, const float* __restrict__ Xq,
    const float* __restrict__ Xv, const bf16* __restrict__ WT,
    const float* __restrict__ bk, const float* __restrict__ bq,
    const float* __restrict__ bv,
    bf16* __restrict__ kp, bf16* __restrict__ qp, bf16* __restrict__ vpT)
{
    const int t    = blockIdx.y;
    const int lane = threadIdx.x & 63;
    const int wave = threadIdx.x >> 6;
    const int lq   = lane & 15;
    const int lg   = lane >> 4;
    const int row0 = blockIdx.x * 64 + wave * 16;

    const float* X    = (t == 0) ? Xk : (t == 1) ? Xq : Xv;
    const float* bias = (t == 0) ? bk : (t == 1) ? bq : bv;
    const bf16*  Wt   = WT + (size_t)t * (Hq * Cq);

    const float* Xrow = X + (size_t)(row0 + lq) * Cq + lg * 8;

    f32x4 acc[4];
#pragma unroll
    for (int i = 0; i < 4; ++i) acc[i] = f32x4{0.f, 0.f, 0.f, 0.f};

    for (int kc = 0; kc < Cq; kc += 32) {
        float4 a0 = *(const float4*)(Xrow + kc);
        float4 a1 = *(const float4*)(Xrow + kc + 4);
        bf16x8 af;
        af[0] = (bf16)a0.x; af[1] = (bf16)a0.y; af[2] = (bf16)a0.z; af[3] = (bf16)a0.w;
        af[4] = (bf16)a1.x; af[5] = (bf16)a1.y; af[6] = (bf16)a1.z; af[7] = (bf16)a1.w;
#pragma unroll
        for (int ht = 0; ht < 4; ++ht) {
            bf16x8 bfB = *(const bf16x8*)(Wt + (size_t)(ht * 16 + lq) * Cq + kc + lg * 8);
            acc[ht] = __builtin_amdgcn_mfma_f32_16x16x32_bf16(af, bfB, acc[ht], 0, 0, 0);
        }
    }

    const float scale = (t == 1) ? 0.044194173824159216f : 1.0f;

    if (t < 2) {
        bf16* dst = (t == 0) ? kp : qp;
#pragma unroll
        for (int ht = 0; ht < 4; ++ht) {
            float bb = bias[ht * 16 + lq];
#pragma unroll
            for (int r = 0; r < 4; ++r) {
                int row = row0 + 4 * lg + r;
                dst[(size_t)row * Hq + ht * 16 + lq] = (bf16)((acc[ht][r] + bb) * scale);
            }
        }
    } else {
#pragma unroll
        for (int ht = 0; ht < 4; ++ht) {
            float bb = bias[ht * 16 + lq];
            bf16x4 pk;
#pragma unroll
            for (int r = 0; r < 4; ++r) pk[r] = (bf16)(acc[ht][r] + bb);
            int rowg = row0 + 4 * lg;
            int bidx = rowg >> 12;
            int tt   = rowg & 4095;
            int h    = ht * 16 + lq;
            *(bf16x4*)(vpT + (((size_t)(bidx * Hq + h)) << 12) + tt) = pk;
        }
    }
}

// ---------------------------------------------------------------------------
// Kernel 3: causal flash attention, split-K, REGISTER-PREFETCH PIPELINE.
// One wave per (b, q-tile of 16, k-chunk of 512).  K/V fragments for tile
// it+1 are loaded into a ping-pong register set BEFORE computing tile it,
// so LLC latency (~500-700cy) hides under the softmax+MFMA of the current
// tile instead of sitting in the dependent chain.
// ---------------------------------------------------------------------------
__global__ __launch_bounds__(64) void attn_kernel(
    const bf16* __restrict__ qp, const bf16* __restrict__ kp,
    const bf16* __restrict__ vpT,
    bf16* __restrict__ PO, float* __restrict__ PML)
{
    __shared__ bf16 P_lds[16][40];

    const int gid  = blockIdx.x;
    const int b    = gid & 3;
    const int qt   = gid >> 2;
    const int qb_  = qt * 16;
    const int c    = blockIdx.y;
    if (c * KC > qb_) return;                 // chunk entirely above diagonal

    const int lane = threadIdx.x;
    const int lq   = lane & 15;
    const int lg   = lane >> 4;

    const bf16* qrow = qp + ((size_t)b * Tq + qb_ + lq) * Hq + lg * 8;
    const bf16x8 Qf0 = *(const bf16x8*)(qrow);
    const bf16x8 Qf1 = *(const bf16x8*)(qrow + 32);

    const bf16* Kb = kp  + (size_t)b * Tq * Hq;
    const bf16* Vb = vpT + (size_t)b * Hq * Tq;

    f32x4 o[4];
#pragma unroll
    for (int i = 0; i < 4; ++i) o[i] = f32x4{0.f, 0.f, 0.f, 0.f};
    float m = -INFINITY, l = 0.f;

    const int nfull = qb_ >> 5;               // diagonal tile index
    const int t0 = c * (KC / 32);
    const int t1 = min(nfull, t0 + (KC / 32) - 1);

    // ---- ping-pong K/V register fragments (A / B sets) ----
    bf16x8 kA0, kA1, kA2, kA3, vA0, vA1, vA2, vA3;
    bf16x8 kB0, kB1, kB2, kB3, vB0, vB1, vB2, vB3;

#define LOAD_TILE(K0, K1, K2, K3, V0, V1, V2, V3, IT)                          \
    do {                                                                       \
        const int kb0_ = (IT) * 32;                                            \
        const bf16* kr_ = Kb + (size_t)(kb0_ + lq) * Hq + lg * 8;              \
        K0 = *(const bf16x8*)(kr_);                                            \
        K1 = *(const bf16x8*)(kr_ + 32);                                       \
        K2 = *(const bf16x8*)(kr_ + 16 * Hq);                                  \
        K3 = *(const bf16x8*)(kr_ + 16 * Hq + 32);                             \
        const bf16* vr_ = Vb + (size_t)lq * Tq + kb0_ + lg * 8;                \
        V0 = *(const bf16x8*)(vr_);                                            \
        V1 = *(const bf16x8*)(vr_ + 16 * Tq);                                  \
        V2 = *(const bf16x8*)(vr_ + 32 * Tq);                                  \
        V3 = *(const bf16x8*)(vr_ + 48 * Tq);                                  \
    } while (0)

#define COMPUTE_TILE(K0, K1, K2, K3, V0, V1, V2, V3, IT)                       \
    do {                                                                       \
        const int kb0_ = (IT) * 32;                                            \
        f32x4 s0, s1;                                                          \
        f32x4 z_ = f32x4{0.f, 0.f, 0.f, 0.f};                                  \
        __builtin_amdgcn_s_setprio(1);                                         \
        s0 = __builtin_amdgcn_mfma_f32_16x16x32_bf16(K0, Qf0, z_, 0, 0, 0);    \
        s0 = __builtin_amdgcn_mfma_f32_16x16x32_bf16(K1, Qf1, s0, 0, 0, 0);    \
        s1 = __builtin_amdgcn_mfma_f32_16x16x32_bf16(K2, Qf0, z_, 0, 0, 0);    \
        s1 = __builtin_amdgcn_mfma_f32_16x16x32_bf16(K3, Qf1, s1, 0, 0, 0);    \
        __builtin_amdgcn_s_setprio(0);                                         \
        if ((IT) == nfull) {                                                   \
            const int qg_ = qb_ + lq;                                          \
            _Pragma("unroll")                                                  \
            for (int r = 0; r < 4; ++r) {                                      \
                if (kb0_ + 4 * lg + r > qg_)      s0[r] = -INFINITY;           \
                if (kb0_ + 16 + 4 * lg + r > qg_) s1[r] = -INFINITY;           \
            }                                                                  \
        }                                                                      \
        float tmax = fmaxf(fmaxf(fmaxf(s0[0], s0[1]), fmaxf(s0[2], s0[3])),    \
                           fmaxf(fmaxf(s1[0], s1[1]), fmaxf(s1[2], s1[3])));   \
        tmax = fmaxf(tmax, __shfl_xor(tmax, 16, 64));                          \
        tmax = fmaxf(tmax, __shfl_xor(tmax, 32, 64));                          \
        const float mnew = fmaxf(m, tmax);                                     \
        const float corr = __expf(m - mnew);                                   \
        float p0[4], p1[4];                                                    \
        _Pragma("unroll")                                                      \
        for (int r = 0; r < 4; ++r) {                                          \
            p0[r] = __expf(s0[r] - mnew);                                      \
            p1[r] = __expf(s1[r] - mnew);                                      \
        }                                                                      \
        float psum = (p0[0] + p0[1] + p0[2] + p0[3]) +                         \
                     (p1[0] + p1[1] + p1[2] + p1[3]);                          \
        psum += __shfl_xor(psum, 16, 64);                                      \
        psum += __shfl_xor(psum, 32, 64);                                      \
        l = l * corr + psum;                                                   \
        m = mnew;                                                              \
        bf16x4 w0, w1;                                                         \
        _Pragma("unroll")                                                      \
        for (int r = 0; r < 4; ++r) { w0[r] = (bf16)p0[r]; w1[r] = (bf16)p1[r]; } \
        *(bf16x4*)(&P_lds[lq][4 * lg])      = w0;                              \
        *(bf16x4*)(&P_lds[lq][16 + 4 * lg]) = w1;                              \
        _Pragma("unroll")                                                      \
        for (int ht = 0; ht < 4; ++ht) {                                       \
            o[ht][0] *= corr; o[ht][1] *= corr;                                \
            o[ht][2] *= corr; o[ht][3] *= corr;                                \
        }                                                                      \
        const bf16x8 Pf = *(const bf16x8*)(&P_lds[lq][8 * lg]);                \
        __builtin_amdgcn_s_setprio(1);                                         \
        o[0] = __builtin_amdgcn_mfma_f32_16x16x32_bf16(V0, Pf, o[0], 0, 0, 0); \
        o[1] = __builtin_amdgcn_mfma_f32_16x16x32_bf16(V1, Pf, o[1], 0, 0, 0); \
        o[2] = __builtin_amdgcn_mfma_f32_16x16x32_bf16(V2, Pf, o[2], 0, 0, 0); \
        o[3] = __builtin_amdgcn_mfma_f32_16x16x32_bf16(V3, Pf, o[3], 0, 0, 0); \
        __builtin_amdgcn_s_setprio(0);                                         \
    } while (0)

    // ---- software-pipelined main loop (2-deep ping-pong) ----
    LOAD_TILE(kA0, kA1, kA2, kA3, vA0, vA1, vA2, vA3, t0);
    int it = t0;
    for (; it + 2 <= t1; it += 2) {
        LOAD_TILE(kB0, kB1, kB2, kB3, vB0, vB1, vB2, vB3, it + 1);
        COMPUTE_TILE(kA0, kA1, kA2, kA3, vA0, vA1, vA2, vA3, it);
        LOAD_TILE(kA0, kA1, kA2, kA3, vA0, vA1, vA2, vA3, it + 2);
        COMPUTE_TILE(kB0, kB1, kB2, kB3, vB0, vB1, vB2, vB3, it + 1);
    }
    if (it + 1 <= t1) {
        LOAD_TILE(kB0, kB1, kB2, kB3, vB0, vB1, vB2, vB3, it + 1);
        COMPUTE_TILE(kA0, kA1, kA2, kA3, vA0, vA1, vA2, vA3, it);
        COMPUTE_TILE(kB0, kB1, kB2, kB3, vB0, vB1, vB2, vB3, it + 1);
    } else {
        COMPUTE_TILE(kA0, kA1, kA2, kA3, vA0, vA1, vA2, vA3, it);
    }
#undef LOAD_TILE
#undef COMPUTE_TILE

    // ---- epilogue: normalized bf16 partial + (m, l) ----
    const float inv = 1.0f / l;
    const size_t slot = (size_t)(b * 256 + qt) * NCH_MAX + c;
    bf16* po = PO + slot * (16 * 64);
#pragma unroll
    for (int ht = 0; ht < 4; ++ht) {
        bf16x4 pk;
#pragma unroll
        for (int r = 0; r < 4; ++r) pk[r] = (bf16)(o[ht][r] * inv);
        *(bf16x4*)(po + lq * 64 + ht * 16 + 4 * lg) = pk;
    }
    if (lg == 0) {
        PML[slot * 32 + lq]      = m;
        PML[slot * 32 + 16 + lq] = l;
    }
}

// ---------------------------------------------------------------------------
// Kernel 4: combine split-K partials.  256 threads per block, one (b,qt) per
// block; thread = (row = tid>>4, h-quad = (tid&15)*4).  Vectorized, no
// serial row loop.
// ---------------------------------------------------------------------------
__global__ __launch_bounds__(256) void combine_kernel(
    const bf16* __restrict__ PO, const float* __restrict__ PML,
    float* __restrict__ out)
{
    const int gid = blockIdx.x;
    const int b   = gid & 3;
    const int qt  = gid >> 2;
    const int qb_ = qt * 16;
    const int nch = (qb_ / KC) + 1;
    const int tid = threadIdx.x;
    const int r   = tid >> 4;          // 0..15
    const int hq  = (tid & 15) * 4;    // 0,4,..,60
    const size_t slot0 = (size_t)(b * 256 + qt) * NCH_MAX;

    float mx = -INFINITY;
    for (int c = 0; c < nch; ++c)
        mx = fmaxf(mx, PML[(slot0 + c) * 32 + r]);

    float L = 0.f;
    float a0 = 0.f, a1 = 0.f, a2 = 0.f, a3 = 0.f;
    for (int c = 0; c < nch; ++c) {
        const float mm = PML[(slot0 + c) * 32 + r];
        const float ll = PML[(slot0 + c) * 32 + 16 + r];
        const float w  = ll * __expf(mm - mx);
        L += w;
        bf16x4 p = *(const bf16x4*)(PO + (slot0 + c) * (16 * 64) + r * 64 + hq);
        a0 += w * (float)p[0];
        a1 += w * (float)p[1];
        a2 += w * (float)p[2];
        a3 += w * (float)p[3];
    }
    const float inv = 1.0f / L;
    float4 st = { a0 * inv, a1 * inv, a2 * inv, a3 * inv };
    *(float4*)(out + ((size_t)b * Tq + qb_ + r) * Hq + hq) = st;
}

// ---------------------------------------------------------------------------
extern "C" void kernel_launch(void* const* d_in, const int* in_sizes, int n_in,
                              void* d_out, int out_size, void* d_ws, size_t ws_size,
                              hipStream_t stream)
{
    const float* k  = (const float*)d_in[0];
    const float* v  = (const float*)d_in[1];
    const float* q  = (const float*)d_in[2];
    // d_in[3] = mask: exactly tril(ones) -> causality hard-coded, never read
    const float* kW = (const float*)d_in[4];
    const float* kb = (const float*)d_in[5];
    const float* vW = (const float*)d_in[6];
    const float* vb = (const float*)d_in[7];
    const float* qW = (const float*)d_in[8];
    const float* qb = (const float*)d_in[9];
    float* out = (float*)d_out;

    // workspace layout:
    //   WT   [3][64][512] bf16      196608 B
    //   kp   [B*T][64]   bf16      2097152 B
    //   qp   [B*T][64]   bf16      2097152 B
    //   vpT  [B][64][T]  bf16      2097152 B
    //   PO   [B][256][8][16][64] bf16  16777216 B
    //   PML  [B][256][8][2][16]  f32    1048576 B
    char* ws = (char*)d_ws;
    bf16*  WT  = (bf16*)(ws);
    bf16*  kp  = (bf16*)(ws + 196608);
    bf16*  qp  = (bf16*)(ws + 196608 + 2097152);
    bf16*  vpT = (bf16*)(ws + 196608 + 2 * 2097152);
    bf16*  PO  = (bf16*)(ws + 196608 + 3 * 2097152);
    float* PML = (float*)(ws + 196608 + 3 * 2097152 + 16777216);

    hipLaunchKernelGGL(prep_weights_kernel, dim3(384), dim3(256), 0, stream,
                       kW, qW, vW, WT);
    hipLaunchKernelGGL(proj_kernel, dim3(256, 3), dim3(256), 0, stream,
                       k, q, v, WT, kb, qb, vb, kp, qp, vpT);
    hipLaunchKernelGGL(attn_kernel, dim3(1024, NCH_MAX), dim3(64), 0, stream,
                       qp, kp, vpT, PO, PML);
    hipLaunchKernelGGL(combine_kernel, dim3(1024), dim3(256), 0, stream,
                       PO, PML, out);
}

// Round 4
// 96.097 us; speedup vs baseline: 1.6934x; 1.2664x over previous
//
#include <hip/hip_runtime.h>
#include <hip/hip_bf16.h>

#define Bq 4
#define Tq 4096
#define Cq 512
#define Hq 64
#define KC 512           // k-chunk width per wave (16 tiles of 32)
#define NCH_MAX 8        // 4096 / 512

using bf16  = __bf16;
using bf16x8 = __attribute__((ext_vector_type(8))) __bf16;
using bf16x4 = __attribute__((ext_vector_type(4))) __bf16;
using f32x4  = __attribute__((ext_vector_type(4))) float;

// ---------------------------------------------------------------------------
// Kernel 1: transpose + bf16-cast the three weight matrices: WT[t][h][c]
// ---------------------------------------------------------------------------
__global__ __launch_bounds__(256) void prep_weights_kernel(
    const float* __restrict__ kW, const float* __restrict__ qW,
    const float* __restrict__ vW, bf16* __restrict__ WT)
{
    int i = blockIdx.x * 256 + threadIdx.x;   // 3*64*512 = 98304 total
    int t = i >> 15;
    int r = i & 32767;
    int h = r >> 9;
    int c = r & 511;
    const float* W = (t == 0) ? kW : (t == 1) ? qW : vW;
    WT[i] = (bf16)W[c * Hq + h];
}

// ---------------------------------------------------------------------------
// Kernel 2: projections via MFMA 16x16x32 bf16.  unroll-4 on the K loop to
// keep more X loads in flight (latency-limited at 2.2x HBM floor before).
// ---------------------------------------------------------------------------
__global__ __launch_bounds__(256) void proj_kernel(
    const float* __restrict__ Xk, const float* __restrict__ Xq,
    const float* __restrict__ Xv, const bf16* __restrict__ WT,
    const float* __restrict__ bk, const float* __restrict__ bq,
    const float* __restrict__ bv,
    bf16* __restrict__ kp, bf16* __restrict__ qp, bf16* __restrict__ vpT)
{
    const int t    = blockIdx.y;
    const int lane = threadIdx.x & 63;
    const int wave = threadIdx.x >> 6;
    const int lq   = lane & 15;
    const int lg   = lane >> 4;
    const int row0 = blockIdx.x * 64 + wave * 16;

    const float* X    = (t == 0) ? Xk : (t == 1) ? Xq : Xv;
    const float* bias = (t == 0) ? bk : (t == 1) ? bq : bv;
    const bf16*  Wt   = WT + (size_t)t * (Hq * Cq);

    const float* Xrow = X + (size_t)(row0 + lq) * Cq + lg * 8;

    f32x4 acc[4];
#pragma unroll
    for (int i = 0; i < 4; ++i) acc[i] = f32x4{0.f, 0.f, 0.f, 0.f};

#pragma unroll 4
    for (int kc = 0; kc < Cq; kc += 32) {
        float4 a0 = *(const float4*)(Xrow + kc);
        float4 a1 = *(const float4*)(Xrow + kc + 4);
        bf16x8 af;
        af[0] = (bf16)a0.x; af[1] = (bf16)a0.y; af[2] = (bf16)a0.z; af[3] = (bf16)a0.w;
        af[4] = (bf16)a1.x; af[5] = (bf16)a1.y; af[6] = (bf16)a1.z; af[7] = (bf16)a1.w;
#pragma unroll
        for (int ht = 0; ht < 4; ++ht) {
            bf16x8 bfB = *(const bf16x8*)(Wt + (size_t)(ht * 16 + lq) * Cq + kc + lg * 8);
            acc[ht] = __builtin_amdgcn_mfma_f32_16x16x32_bf16(af, bfB, acc[ht], 0, 0, 0);
        }
    }

    const float scale = (t == 1) ? 0.044194173824159216f : 1.0f;

    if (t < 2) {
        bf16* dst = (t == 0) ? kp : qp;
#pragma unroll
        for (int ht = 0; ht < 4; ++ht) {
            float bb = bias[ht * 16 + lq];
#pragma unroll
            for (int r = 0; r < 4; ++r) {
                int row = row0 + 4 * lg + r;
                dst[(size_t)row * Hq + ht * 16 + lq] = (bf16)((acc[ht][r] + bb) * scale);
            }
        }
    } else {
#pragma unroll
        for (int ht = 0; ht < 4; ++ht) {
            float bb = bias[ht * 16 + lq];
            bf16x4 pk;
#pragma unroll
            for (int r = 0; r < 4; ++r) pk[r] = (bf16)(acc[ht][r] + bb);
            int rowg = row0 + 4 * lg;
            int bidx = rowg >> 12;
            int tt   = rowg & 4095;
            int h    = ht * 16 + lq;
            *(bf16x4*)(vpT + (((size_t)(bidx * Hq + h)) << 12) + tt) = pk;
        }
    }
}

// ---------------------------------------------------------------------------
// Kernel 3: causal flash attention, split-K, 32 q-rows/wave, XCD-affinity.
//  - Each wave owns TWO 16-row q-subtiles (U: rows qb..qb+15, W: +16..+31)
//    that share the same K/V register fragments -> K/V cache traffic halves.
//  - blockIdx.x swizzle: xcd_slot = x&7, batch = slot>>1  => each batch's
//    kp/qp/vpT (1.5 MB) stays resident in its 2 XCDs' L2.
//  - 2-deep ping-pong K/V register prefetch; s_setprio around MFMA clusters.
// ---------------------------------------------------------------------------
__global__ __launch_bounds__(64) void attn_kernel(
    const bf16* __restrict__ qp, const bf16* __restrict__ kp,
    const bf16* __restrict__ vpT,
    bf16* __restrict__ PO, float* __restrict__ PML)
{
    __shared__ bf16 P_lds[2][16][40];

    const int x = blockIdx.x;                 // 512 = 4 batches * 128 a-tiles
    const int s = x & 7;                      // XCD slot (assumes bid%8 mapping)
    const int b = s >> 1;                     // batch pinned to XCD pair
    const int a = ((x >> 3) << 1) | (s & 1);  // 0..127: 32-row q-tile index
    const int qb = a * 32;
    const int c = blockIdx.y;
    if (c * KC > qb + 31) return;             // chunk entirely above diagonal

    const int lane = threadIdx.x;
    const int lq   = lane & 15;
    const int lg   = lane >> 4;
    const int qgU  = qb + lq;
    const int qgW  = qb + 16 + lq;

    const bf16* qrowU = qp + ((size_t)b * Tq + qb + lq) * Hq + lg * 8;
    const bf16x8 QU0 = *(const bf16x8*)(qrowU);
    const bf16x8 QU1 = *(const bf16x8*)(qrowU + 32);
    const bf16* qrowW = qp + ((size_t)b * Tq + qb + 16 + lq) * Hq + lg * 8;
    const bf16x8 QW0 = *(const bf16x8*)(qrowW);
    const bf16x8 QW1 = *(const bf16x8*)(qrowW + 32);

    const bf16* Kb = kp  + (size_t)b * Tq * Hq;
    const bf16* Vb = vpT + (size_t)b * Hq * Tq;

    f32x4 oU[4], oW[4];
#pragma unroll
    for (int i = 0; i < 4; ++i) { oU[i] = f32x4{0.f,0.f,0.f,0.f}; oW[i] = f32x4{0.f,0.f,0.f,0.f}; }
    float mU = -INFINITY, lU = 0.f, mW = -INFINITY, lW = 0.f;

    const int t0 = c * (KC / 32);
    const int t1 = min(a, t0 + (KC / 32) - 1);   // diagonal tile for BOTH subtiles is 'a'

    bf16x8 kA0, kA1, kA2, kA3, vA0, vA1, vA2, vA3;
    bf16x8 kB0, kB1, kB2, kB3, vB0, vB1, vB2, vB3;

#define LOAD_TILE(K0, K1, K2, K3, V0, V1, V2, V3, IT)                          \
    do {                                                                       \
        const int kb0_ = (IT) * 32;                                            \
        const bf16* kr_ = Kb + (size_t)(kb0_ + lq) * Hq + lg * 8;              \
        K0 = *(const bf16x8*)(kr_);                                            \
        K1 = *(const bf16x8*)(kr_ + 32);                                       \
        K2 = *(const bf16x8*)(kr_ + 16 * Hq);                                  \
        K3 = *(const bf16x8*)(kr_ + 16 * Hq + 32);                             \
        const bf16* vr_ = Vb + (size_t)lq * Tq + kb0_ + lg * 8;                \
        V0 = *(const bf16x8*)(vr_);                                            \
        V1 = *(const bf16x8*)(vr_ + 16 * Tq);                                  \
        V2 = *(const bf16x8*)(vr_ + 32 * Tq);                                  \
        V3 = *(const bf16x8*)(vr_ + 48 * Tq);                                  \
    } while (0)

#define COMPUTE_TILE(K0, K1, K2, K3, V0, V1, V2, V3, IT)                       \
    do {                                                                       \
        const int kb0_ = (IT) * 32;                                            \
        f32x4 z_ = f32x4{0.f, 0.f, 0.f, 0.f};                                  \
        f32x4 sU0, sU1, sW0, sW1;                                              \
        __builtin_amdgcn_s_setprio(1);                                         \
        sU0 = __builtin_amdgcn_mfma_f32_16x16x32_bf16(K0, QU0, z_, 0, 0, 0);   \
        sU0 = __builtin_amdgcn_mfma_f32_16x16x32_bf16(K1, QU1, sU0, 0, 0, 0);  \
        sU1 = __builtin_amdgcn_mfma_f32_16x16x32_bf16(K2, QU0, z_, 0, 0, 0);   \
        sU1 = __builtin_amdgcn_mfma_f32_16x16x32_bf16(K3, QU1, sU1, 0, 0, 0);  \
        sW0 = __builtin_amdgcn_mfma_f32_16x16x32_bf16(K0, QW0, z_, 0, 0, 0);   \
        sW0 = __builtin_amdgcn_mfma_f32_16x16x32_bf16(K1, QW1, sW0, 0, 0, 0);  \
        sW1 = __builtin_amdgcn_mfma_f32_16x16x32_bf16(K2, QW0, z_, 0, 0, 0);   \
        sW1 = __builtin_amdgcn_mfma_f32_16x16x32_bf16(K3, QW1, sW1, 0, 0, 0);  \
        __builtin_amdgcn_s_setprio(0);                                         \
        if ((IT) == a) {                                                       \
            _Pragma("unroll")                                                  \
            for (int r = 0; r < 4; ++r) {                                      \
                if (kb0_ + 4 * lg + r > qgU)      sU0[r] = -INFINITY;          \
                if (kb0_ + 16 + 4 * lg + r > qgU) sU1[r] = -INFINITY;          \
                if (kb0_ + 4 * lg + r > qgW)      sW0[r] = -INFINITY;          \
                if (kb0_ + 16 + 4 * lg + r > qgW) sW1[r] = -INFINITY;          \
            }                                                                  \
        }                                                                      \
        float tU = fmaxf(fmaxf(fmaxf(sU0[0], sU0[1]), fmaxf(sU0[2], sU0[3])),  \
                         fmaxf(fmaxf(sU1[0], sU1[1]), fmaxf(sU1[2], sU1[3]))); \
        float tW = fmaxf(fmaxf(fmaxf(sW0[0], sW0[1]), fmaxf(sW0[2], sW0[3])),  \
                         fmaxf(fmaxf(sW1[0], sW1[1]), fmaxf(sW1[2], sW1[3]))); \
        tU = fmaxf(tU, __shfl_xor(tU, 16, 64));                                \
        tW = fmaxf(tW, __shfl_xor(tW, 16, 64));                                \
        tU = fmaxf(tU, __shfl_xor(tU, 32, 64));                                \
        tW = fmaxf(tW, __shfl_xor(tW, 32, 64));                                \
        const float mnU = fmaxf(mU, tU);                                       \
        const float mnW = fmaxf(mW, tW);                                       \
        const float crU = __expf(mU - mnU);                                    \
        const float crW = __expf(mW - mnW);                                    \
        float pU0[4], pU1[4], pW0[4], pW1[4];                                  \
        _Pragma("unroll")                                                      \
        for (int r = 0; r < 4; ++r) {                                          \
            pU0[r] = __expf(sU0[r] - mnU); pU1[r] = __expf(sU1[r] - mnU);      \
            pW0[r] = __expf(sW0[r] - mnW); pW1[r] = __expf(sW1[r] - mnW);      \
        }                                                                      \
        float psU = (pU0[0]+pU0[1]+pU0[2]+pU0[3]) + (pU1[0]+pU1[1]+pU1[2]+pU1[3]); \
        float psW = (pW0[0]+pW0[1]+pW0[2]+pW0[3]) + (pW1[0]+pW1[1]+pW1[2]+pW1[3]); \
        psU += __shfl_xor(psU, 16, 64);                                        \
        psW += __shfl_xor(psW, 16, 64);                                        \
        psU += __shfl_xor(psU, 32, 64);                                        \
        psW += __shfl_xor(psW, 32, 64);                                        \
        lU = lU * crU + psU;  mU = mnU;                                        \
        lW = lW * crW + psW;  mW = mnW;                                        \
        bf16x4 u0, u1, w0, w1;                                                 \
        _Pragma("unroll")                                                      \
        for (int r = 0; r < 4; ++r) {                                          \
            u0[r] = (bf16)pU0[r]; u1[r] = (bf16)pU1[r];                        \
            w0[r] = (bf16)pW0[r]; w1[r] = (bf16)pW1[r];                        \
        }                                                                      \
        *(bf16x4*)(&P_lds[0][lq][4 * lg])      = u0;                           \
        *(bf16x4*)(&P_lds[0][lq][16 + 4 * lg]) = u1;                           \
        *(bf16x4*)(&P_lds[1][lq][4 * lg])      = w0;                           \
        *(bf16x4*)(&P_lds[1][lq][16 + 4 * lg]) = w1;                           \
        _Pragma("unroll")                                                      \
        for (int ht = 0; ht < 4; ++ht) {                                       \
            oU[ht][0] *= crU; oU[ht][1] *= crU; oU[ht][2] *= crU; oU[ht][3] *= crU; \
            oW[ht][0] *= crW; oW[ht][1] *= crW; oW[ht][2] *= crW; oW[ht][3] *= crW; \
        }                                                                      \
        const bf16x8 PfU = *(const bf16x8*)(&P_lds[0][lq][8 * lg]);            \
        const bf16x8 PfW = *(const bf16x8*)(&P_lds[1][lq][8 * lg]);            \
        __builtin_amdgcn_s_setprio(1);                                         \
        oU[0] = __builtin_amdgcn_mfma_f32_16x16x32_bf16(V0, PfU, oU[0], 0, 0, 0); \
        oU[1] = __builtin_amdgcn_mfma_f32_16x16x32_bf16(V1, PfU, oU[1], 0, 0, 0); \
        oU[2] = __builtin_amdgcn_mfma_f32_16x16x32_bf16(V2, PfU, oU[2], 0, 0, 0); \
        oU[3] = __builtin_amdgcn_mfma_f32_16x16x32_bf16(V3, PfU, oU[3], 0, 0, 0); \
        oW[0] = __builtin_amdgcn_mfma_f32_16x16x32_bf16(V0, PfW, oW[0], 0, 0, 0); \
        oW[1] = __builtin_amdgcn_mfma_f32_16x16x32_bf16(V1, PfW, oW[1], 0, 0, 0); \
        oW[2] = __builtin_amdgcn_mfma_f32_16x16x32_bf16(V2, PfW, oW[2], 0, 0, 0); \
        oW[3] = __builtin_amdgcn_mfma_f32_16x16x32_bf16(V3, PfW, oW[3], 0, 0, 0); \
        __builtin_amdgcn_s_setprio(0);                                         \
    } while (0)

    // ---- software-pipelined main loop (2-deep ping-pong) ----
    LOAD_TILE(kA0, kA1, kA2, kA3, vA0, vA1, vA2, vA3, t0);
    int it = t0;
    for (; it + 2 <= t1; it += 2) {
        LOAD_TILE(kB0, kB1, kB2, kB3, vB0, vB1, vB2, vB3, it + 1);
        COMPUTE_TILE(kA0, kA1, kA2, kA3, vA0, vA1, vA2, vA3, it);
        LOAD_TILE(kA0, kA1, kA2, kA3, vA0, vA1, vA2, vA3, it + 2);
        COMPUTE_TILE(kB0, kB1, kB2, kB3, vB0, vB1, vB2, vB3, it + 1);
    }
    if (it + 1 <= t1) {
        LOAD_TILE(kB0, kB1, kB2, kB3, vB0, vB1, vB2, vB3, it + 1);
        COMPUTE_TILE(kA0, kA1, kA2, kA3, vA0, vA1, vA2, vA3, it);
        COMPUTE_TILE(kB0, kB1, kB2, kB3, vB0, vB1, vB2, vB3, it + 1);
    } else {
        COMPUTE_TILE(kA0, kA1, kA2, kA3, vA0, vA1, vA2, vA3, it);
    }
#undef LOAD_TILE
#undef COMPUTE_TILE

    // ---- epilogue: normalized bf16 partials + (m, l) for U and W ----
    const float invU = 1.0f / lU;
    const float invW = 1.0f / lW;
    const size_t slotU = (size_t)(b * 256 + 2 * a) * NCH_MAX + c;
    const size_t slotW = slotU + NCH_MAX;
    bf16* poU = PO + slotU * (16 * 64);
    bf16* poW = PO + slotW * (16 * 64);
#pragma unroll
    for (int ht = 0; ht < 4; ++ht) {
        bf16x4 pkU, pkW;
#pragma unroll
        for (int r = 0; r < 4; ++r) {
            pkU[r] = (bf16)(oU[ht][r] * invU);
            pkW[r] = (bf16)(oW[ht][r] * invW);
        }
        *(bf16x4*)(poU + lq * 64 + ht * 16 + 4 * lg) = pkU;
        *(bf16x4*)(poW + lq * 64 + ht * 16 + 4 * lg) = pkW;
    }
    if (lg == 0) {
        PML[slotU * 32 + lq]      = mU;
        PML[slotU * 32 + 16 + lq] = lU;
        PML[slotW * 32 + lq]      = mW;
        PML[slotW * 32 + 16 + lq] = lW;
    }
}

// ---------------------------------------------------------------------------
// Kernel 4: combine split-K partials.  256 threads per block, one (b,qt) per
// block; thread = (row = tid>>4, h-quad = (tid&15)*4).
// ---------------------------------------------------------------------------
__global__ __launch_bounds__(256) void combine_kernel(
    const bf16* __restrict__ PO, const float* __restrict__ PML,
    float* __restrict__ out)
{
    const int gid = blockIdx.x;
    const int b   = gid & 3;
    const int qt  = gid >> 2;
    const int qb_ = qt * 16;
    const int nch = (qb_ / KC) + 1;
    const int tid = threadIdx.x;
    const int r   = tid >> 4;          // 0..15
    const int hq  = (tid & 15) * 4;    // 0,4,..,60
    const size_t slot0 = (size_t)(b * 256 + qt) * NCH_MAX;

    float mx = -INFINITY;
    for (int c = 0; c < nch; ++c)
        mx = fmaxf(mx, PML[(slot0 + c) * 32 + r]);

    float L = 0.f;
    float a0 = 0.f, a1 = 0.f, a2 = 0.f, a3 = 0.f;
    for (int c = 0; c < nch; ++c) {
        const float mm = PML[(slot0 + c) * 32 + r];
        const float ll = PML[(slot0 + c) * 32 + 16 + r];
        const float w  = ll * __expf(mm - mx);
        L += w;
        bf16x4 p = *(const bf16x4*)(PO + (slot0 + c) * (16 * 64) + r * 64 + hq);
        a0 += w * (float)p[0];
        a1 += w * (float)p[1];
        a2 += w * (float)p[2];
        a3 += w * (float)p[3];
    }
    const float inv = 1.0f / L;
    float4 st = { a0 * inv, a1 * inv, a2 * inv, a3 * inv };
    *(float4*)(out + ((size_t)b * Tq + qb_ + r) * Hq + hq) = st;
}

// ---------------------------------------------------------------------------
extern "C" void kernel_launch(void* const* d_in, const int* in_sizes, int n_in,
                              void* d_out, int out_size, void* d_ws, size_t ws_size,
                              hipStream_t stream)
{
    const float* k  = (const float*)d_in[0];
    const float* v  = (const float*)d_in[1];
    const float* q  = (const float*)d_in[2];
    // d_in[3] = mask: exactly tril(ones) -> causality hard-coded, never read
    const float* kW = (const float*)d_in[4];
    const float* kb = (const float*)d_in[5];
    const float* vW = (const float*)d_in[6];
    const float* vb = (const float*)d_in[7];
    const float* qW = (const float*)d_in[8];
    const float* qb = (const float*)d_in[9];
    float* out = (float*)d_out;

    // workspace layout:
    //   WT   [3][64][512] bf16      196608 B
    //   kp   [B*T][64]   bf16      2097152 B
    //   qp   [B*T][64]   bf16      2097152 B
    //   vpT  [B][64][T]  bf16      2097152 B
    //   PO   [B][256][8][16][64] bf16  16777216 B
    //   PML  [B][256][8][2][16]  f32    1048576 B
    char* ws = (char*)d_ws;
    bf16*  WT  = (bf16*)(ws);
    bf16*  kp  = (bf16*)(ws + 196608);
    bf16*  qp  = (bf16*)(ws + 196608 + 2097152);
    bf16*  vpT = (bf16*)(ws + 196608 + 2 * 2097152);
    bf16*  PO  = (bf16*)(ws + 196608 + 3 * 2097152);
    float* PML = (float*)(ws + 196608 + 3 * 2097152 + 16777216);

    hipLaunchKernelGGL(prep_weights_kernel, dim3(384), dim3(256), 0, stream,
                       kW, qW, vW, WT);
    hipLaunchKernelGGL(proj_kernel, dim3(256, 3), dim3(256), 0, stream,
                       k, q, v, WT, kb, qb, vb, kp, qp, vpT);
    hipLaunchKernelGGL(attn_kernel, dim3(512, NCH_MAX), dim3(64), 0, stream,
                       qp, kp, vpT, PO, PML);
    hipLaunchKernelGGL(combine_kernel, dim3(1024), dim3(256), 0, stream,
                       PO, PML, out);
}